// Round 7
// baseline (815.028 us; speedup 1.0000x reference)
//
#include <hip/hip_runtime.h>
#include <hip/hip_fp16.h>
#include <math.h>

typedef _Float16 half_t;
typedef __attribute__((ext_vector_type(8))) _Float16 f16x8;  // MFMA A/B frag
typedef __attribute__((ext_vector_type(4))) float   f32x4;   // MFMA C/D frag
typedef __attribute__((ext_vector_type(4))) float   float4v;

#define IN_F   1536
#define HID    640
#define OUT_F  10
#define NBATCH 65536

#define SB() __builtin_amdgcn_sched_barrier(0)

// ---------- helpers ----------

__device__ __forceinline__ void gll16(const void* g, const void* l) {
    __builtin_amdgcn_global_load_lds(
        (const __attribute__((address_space(1))) unsigned*)g,
        (__attribute__((address_space(3))) unsigned*)l, 16, 0, 0);
}

// exact-GELU via A&S 7.1.26 erf poly (|eps|<=1.5e-7, noise vs f16 rounding)
__device__ __forceinline__ float gelu_fast(float z) {
    float x  = 0.70710678118654752f * z;
    float ax = fabsf(x);
    float t  = 1.0f / (1.0f + 0.3275911f * ax);
    float p  = t * (0.254829592f +
               t * (-0.284496736f +
               t * (1.421413741f +
               t * (-1.453152027f +
               t * 1.061405429f))));
    float e  = __expf(-ax * ax);
    float er = 1.0f - p * e;
    er = (x < 0.0f) ? -er : er;
    return 0.5f * z * (1.0f + er);
}

// ---------- prep: mask dtype detection + masked weight build ----------

__global__ void k_detect(const unsigned* __restrict__ m, int nDwords, int* flags) {
    int f = 0, g = 0;
    for (int i = blockIdx.x * blockDim.x + threadIdx.x; i < nDwords;
         i += gridDim.x * blockDim.x) {
        unsigned d = m[i];
        f |= (d == 0x3F800000u);
        g |= (d != 0u) & (d != 1u) & (d != 0x3F800000u);
    }
    if (f) atomicOr(&flags[0], 1);
    if (g) atomicOr(&flags[1], 1);
}

__device__ __forceinline__ bool mask_at(const void* mask, int i, int isB, int isF) {
    if (isB) return ((const unsigned char*)mask)[i] != 0;
    if (isF) return ((const float*)mask)[i] != 0.0f;
    return ((const int*)mask)[i] != 0;
}

__global__ void k_mask_all(const float* __restrict__ W1, const float* __restrict__ W2,
                           const float* __restrict__ W3,
                           const void* __restrict__ m1, const void* __restrict__ m2,
                           const void* __restrict__ m3,
                           half_t* __restrict__ W1h, half_t* __restrict__ W2h,
                           float* __restrict__ W3m, const int* __restrict__ flags) {
    const int isB = flags[1], isF = flags[0];
    const int N1 = HID * IN_F, N2 = HID * HID, N3 = OUT_F * HID;
    const int NT = N1 + N2 + N3;
    for (int i = blockIdx.x * blockDim.x + threadIdx.x; i < NT;
         i += gridDim.x * blockDim.x) {
        if (i < N1) {
            W1h[i] = mask_at(m1, i, isB, isF) ? (half_t)W1[i] : (half_t)0.0f;
        } else if (i < N1 + N2) {
            int j = i - N1;
            W2h[j] = mask_at(m2, j, isB, isF) ? (half_t)W2[j] : (half_t)0.0f;
        } else {
            int j = i - N1 - N2;
            W3m[j] = mask_at(m3, j, isB, isF) ? W3[j] : 0.0f;
        }
    }
}

// ---------- fused GEMM (+ exact GELU): A direct-to-reg, B gll->LDS ----------
// C[m][n] = gelu( sum_k A[m][k] * W[n][k] ), C f16 [NBATCH][HID].
// Tile 128x320, BK=32, 512 thr = 8 waves (2m x 4n of 64x80), 20 MFMA/wave/step.
// A: loaded straight to VGPR (32B/lane contiguous), f32->f16 cvt in-reg (AF32).
// B: staged via global_load_lds into 3-deep LDS ring, 24KB/slab (384 rows incl
//    64 pad rows), pair-packed [192][128B] rows, 8-slot XOR swizzle.
// VMEM queue per iter (issue order A(ks+1) then B(ks+3)):
//   entry of ks: [B(ks+1)3, A(ks)na, B(ks+2)3] -> vmcnt(3) retires A(ks)+older.
//   ks==0: [A0, B0, B1, B2] -> vmcnt(6). ks+2>=NK: vmcnt(0).
template <int K, bool AF32>
__global__ __launch_bounds__(512, 2) void gemm_gelu(
    const void* __restrict__ Ain, const half_t* __restrict__ Bw,
    half_t* __restrict__ Cout) {
    constexpr int NK = K / 32;                 // 48 or 20 (even)
    __shared__ __align__(16) char lds[3 * 24576];   // B ring only

    const int t    = threadIdx.x;
    const int lane = t & 63;
    const int wid  = t >> 6;
    const int wr   = wid >> 2;                 // 0..1  (m)
    const int wc   = wid & 3;                  // 0..3  (n)

    // XCD-bijective swizzle; nwg = 1024 = 8*128. n-fastest: the 2 n-blocks
    // sharing an x panel are adjacent on one XCD's L2.
    const int q       = (int)gridDim.x >> 3;
    const int logical = ((int)blockIdx.x & 7) * q + ((int)blockIdx.x >> 3);
    const int mb  = logical >> 1, nbk = logical & 1;
    const long mBase = (long)mb * 128;
    const int  n0    = nbk * 320;

    // ---- B read addresses (5 n-frags), swizzled pair-packed layout ----
    // byte(nrow,kq) = (nrow>>1)*128 + ((((nrow&1)<<2)|kq) ^ ((nrow>>1)&7))<<4
    int rdB[5];
    {
        const int kq = lane >> 4, r = lane & 15;
#pragma unroll
        for (int n = 0; n < 5; ++n) {
            const int nrow = wc * 80 + n * 16 + r;
            rdB[n] = (nrow >> 1) * 128 +
                     (((((nrow & 1) << 2) | kq) ^ ((nrow >> 1) & 7)) << 4);
        }
    }

    // ---- B staging: 3 gll16/thread, linear dest o=(t+r*512)*16, decode src ----
    const half_t* srcB[3];
    int ldsOffB[3];
#pragma unroll
    for (int r = 0; r < 3; ++r) {
        const int o      = (t + r * 512) * 16;
        const int row128 = o >> 7;
        const int hs     = (o >> 4) & 7;
        const int orig   = hs ^ (row128 & 7);
        const int nrow   = row128 * 2 + (orig >> 2);
        const int kq     = orig & 3;
        srcB[r]   = Bw + (size_t)(n0 + nrow) * K + kq * 8;
        ldsOffB[r] = o;
    }
    auto BSTAGE = [&](int k, int bb) {
#pragma unroll
        for (int r = 0; r < 3; ++r)
            gll16(srcB[r] + (size_t)k * 32, &lds[bb + ldsOffB[r]]);
    };

    // ---- A direct-load bases (4 m-frags) ----
    const float*  baseAf[4];
    const half_t* baseAh[4];
    {
        const int kq = lane >> 4, r = lane & 15;
#pragma unroll
        for (int m = 0; m < 4; ++m) {
            const long row = mBase + wr * 64 + m * 16 + r;
            if constexpr (AF32) baseAf[m] = (const float*)Ain + row * K + kq * 8;
            else                baseAh[m] = (const half_t*)Ain + row * K + kq * 8;
        }
    }

    float4v af[8];                 // AF32: in-flight f32 A (k = kq*8 + 0..7)
    f16x8   avE[4], avO[4];        // !AF32: double-buffered A frags
    auto ALOADF = [&](int k) {
#pragma unroll
        for (int m = 0; m < 4; ++m) {
            af[2 * m]     = *(const float4v*)(baseAf[m] + (size_t)k * 32);
            af[2 * m + 1] = *(const float4v*)(baseAf[m] + (size_t)k * 32 + 4);
        }
    };
    auto ALOADH = [&](int k, f16x8 (&dst)[4]) {
#pragma unroll
        for (int m = 0; m < 4; ++m)
            dst[m] = *(const f16x8*)(baseAh[m] + (size_t)k * 32);
    };

    f32x4 acc[4][5];
#pragma unroll
    for (int m = 0; m < 4; ++m)
#pragma unroll
        for (int n = 0; n < 5; ++n) {
            f32x4 z = {0.f, 0.f, 0.f, 0.f};
            acc[m][n] = z;
        }

    // ---- prologue: A(0) then B(0),B(1),B(2) ----
    if constexpr (AF32) ALOADF(0); else ALOADH(0, avE);
    SB();
    BSTAGE(0, 0); BSTAGE(1, 24576); BSTAGE(2, 49152);
    SB();

    auto ITER = [&](int ks, f16x8 (&cur)[4], f16x8 (&nxt)[4]) {
        if (ks == 0)          asm volatile("s_waitcnt vmcnt(6)" ::: "memory");
        else if (ks + 2 < NK) asm volatile("s_waitcnt vmcnt(3)" ::: "memory");
        else                  asm volatile("s_waitcnt vmcnt(0)" ::: "memory");
        __builtin_amdgcn_s_barrier();                 // READY: B LDS slab ks
        f16x8 av[4];
        if constexpr (AF32) {
#pragma unroll
            for (int m = 0; m < 4; ++m) {
                f16x8 h;
#pragma unroll
                for (int i = 0; i < 4; ++i) {
                    h[i]     = (half_t)af[2 * m][i];
                    h[i + 4] = (half_t)af[2 * m + 1][i];
                }
                av[m] = h;
            }
        } else {
#pragma unroll
            for (int m = 0; m < 4; ++m) av[m] = cur[m];
        }
        const int bb = (ks % 3) * 24576;
        f16x8 bv[5];
#pragma unroll
        for (int n = 0; n < 5; ++n) bv[n] = *(const f16x8*)(&lds[bb + rdB[n]]);
        asm volatile("s_waitcnt lgkmcnt(0)" ::: "memory");
        SB();
        __builtin_amdgcn_s_barrier();                 // CONSUMED slab ks
        if (ks + 1 < NK) {
            if constexpr (AF32) ALOADF(ks + 1);
            else                ALOADH(ks + 1, nxt);
        }
        if (ks + 3 < NK) BSTAGE(ks + 3, bb);          // (ks+3)%3 == ks%3
        SB();
#pragma unroll
        for (int m = 0; m < 4; ++m)
#pragma unroll
            for (int n = 0; n < 5; ++n)
                acc[m][n] = __builtin_amdgcn_mfma_f32_16x16x32_f16(
                    av[m], bv[n], acc[m][n], 0, 0, 0);
    };

    for (int ks = 0; ks < NK; ks += 2) {
        ITER(ks,     avE, avO);
        ITER(ks + 1, avO, avE);
    }

    // epilogue: C/D frag col=lane&15, row=(lane>>4)*4+j (verified mapping)
    const int crow0 = (lane >> 4) * 4;
    const int ccol  = lane & 15;
#pragma unroll
    for (int m = 0; m < 4; ++m)
#pragma unroll
        for (int n = 0; n < 5; ++n)
#pragma unroll
            for (int j = 0; j < 4; ++j) {
                const long row = mBase + wr * 64 + m * 16 + crow0 + j;
                const int  col = n0 + wc * 80 + n * 16 + ccol;
                Cout[row * HID + col] = (half_t)gelu_fast(acc[m][n][j]);
            }
}

// ---------- layer 3: out[b][o] = sum_k h2[b][k] * W3m[o][k], K=640, O=10 ----------
__global__ __launch_bounds__(256) void layer3_kernel(
    const half_t* __restrict__ h2, const float* __restrict__ W3m,
    float* __restrict__ out) {
    const int t = threadIdx.x, lane = t & 63, w = t >> 6;
    float w3r[OUT_F][10];
#pragma unroll
    for (int o = 0; o < OUT_F; ++o)
#pragma unroll
        for (int j = 0; j < 10; ++j)
            w3r[o][j] = W3m[o * HID + j * 64 + lane];

    for (long row = (long)blockIdx.x * 4 + w; row < NBATCH; row += (long)gridDim.x * 4) {
        float acc[OUT_F];
#pragma unroll
        for (int o = 0; o < OUT_F; ++o) acc[o] = 0.f;
        const half_t* hr = h2 + row * HID;
#pragma unroll
        for (int j = 0; j < 10; ++j) {
            const float h = (float)hr[j * 64 + lane];
#pragma unroll
            for (int o = 0; o < OUT_F; ++o) acc[o] += h * w3r[o][j];
        }
#pragma unroll
        for (int o = 0; o < OUT_F; ++o) {
            float v = acc[o];
#pragma unroll
            for (int off = 32; off >= 1; off >>= 1) v += __shfl_xor(v, off);
            if (lane == o) out[row * OUT_F + o] = v;
        }
    }
}

// ---------- launch ----------

extern "C" void kernel_launch(void* const* d_in, const int* in_sizes, int n_in,
                              void* d_out, int out_size, void* d_ws, size_t ws_size,
                              hipStream_t stream) {
    const float* x  = (const float*)d_in[0];
    const float* W1 = (const float*)d_in[1];
    const float* W2 = (const float*)d_in[2];
    const float* W3 = (const float*)d_in[3];
    const void*  m1 = d_in[4];
    const void*  m2 = d_in[5];
    const void*  m3 = d_in[6];
    float* out = (float*)d_out;

    // ws layout: flags | W1h (704 rows: 64 pad) | W2h (704 rows) | W3m | h1 | h2
    char* ws = (char*)d_ws;
    int*    flags = (int*)ws;
    half_t* W1h = (half_t*)(ws + 256);                      // 704*1536*2 = 2162688
    half_t* W2h = (half_t*)(ws + 256 + 2162688);            // 704*640*2  = 901120
    float*  W3m = (float*)(ws + 256 + 2162688 + 901120);    // 25600
    half_t* h1  = (half_t*)(ws + 256 + 2162688 + 901120 + 25600);
    half_t* h2  = (half_t*)((char*)h1 + (size_t)NBATCH * HID * 2);
    // total ~170.9 MB (prev layout used 170.6 OK). Pad rows never consumed.

    hipMemsetAsync(flags, 0, 8, stream);
    k_detect<<<64, 256, 0, stream>>>((const unsigned*)m1, 65536, flags);
    k_mask_all<<<1024, 256, 0, stream>>>(W1, W2, W3, m1, m2, m3, W1h, W2h, W3m, flags);

    gemm_gelu<IN_F, true><<<1024, 512, 0, stream>>>((const void*)x, W1h, h1);
    gemm_gelu<HID, false><<<1024, 512, 0, stream>>>((const void*)h1, W2h, h2);
    layer3_kernel<<<2048, 256, 0, stream>>>(h2, W3m, out);
}

// Round 8
// 575.965 us; speedup vs baseline: 1.4151x; 1.4151x over previous
//
#include <hip/hip_runtime.h>
#include <hip/hip_fp16.h>
#include <math.h>
#include <type_traits>

typedef _Float16 half_t;
typedef __attribute__((ext_vector_type(8))) _Float16 f16x8;  // MFMA A/B frag
typedef __attribute__((ext_vector_type(4))) float   f32x4;   // MFMA C/D frag
typedef __attribute__((ext_vector_type(4))) float   float4v;

#define IN_F   1536
#define HID    640
#define OUT_F  10
#define NBATCH 65536

#define SB() __builtin_amdgcn_sched_barrier(0)

template <int N> using ic = std::integral_constant<int, N>;

// ---------- helpers ----------

// exact-GELU via A&S 7.1.26 erf poly (|eps|<=1.5e-7, noise vs f16 rounding)
__device__ __forceinline__ float gelu_fast(float z) {
    float x  = 0.70710678118654752f * z;
    float ax = fabsf(x);
    float t  = 1.0f / (1.0f + 0.3275911f * ax);
    float p  = t * (0.254829592f +
               t * (-0.284496736f +
               t * (1.421413741f +
               t * (-1.453152027f +
               t * 1.061405429f))));
    float e  = __expf(-ax * ax);
    float er = 1.0f - p * e;
    er = (x < 0.0f) ? -er : er;
    return 0.5f * z * (1.0f + er);
}

// ---------- prep: mask dtype detection + masked weight build ----------

__global__ void k_detect(const unsigned* __restrict__ m, int nDwords, int* flags) {
    int f = 0, g = 0;
    for (int i = blockIdx.x * blockDim.x + threadIdx.x; i < nDwords;
         i += gridDim.x * blockDim.x) {
        unsigned d = m[i];
        f |= (d == 0x3F800000u);
        g |= (d != 0u) & (d != 1u) & (d != 0x3F800000u);
    }
    if (f) atomicOr(&flags[0], 1);
    if (g) atomicOr(&flags[1], 1);
}

__device__ __forceinline__ bool mask_at(const void* mask, int i, int isB, int isF) {
    if (isB) return ((const unsigned char*)mask)[i] != 0;
    if (isF) return ((const float*)mask)[i] != 0.0f;
    return ((const int*)mask)[i] != 0;
}

__global__ void k_mask_all(const float* __restrict__ W1, const float* __restrict__ W2,
                           const float* __restrict__ W3,
                           const void* __restrict__ m1, const void* __restrict__ m2,
                           const void* __restrict__ m3,
                           half_t* __restrict__ W1h, half_t* __restrict__ W2h,
                           float* __restrict__ W3m, const int* __restrict__ flags) {
    const int isB = flags[1], isF = flags[0];
    const int N1 = HID * IN_F, N2 = HID * HID, N3 = OUT_F * HID;
    const int NT = N1 + N2 + N3;
    for (int i = blockIdx.x * blockDim.x + threadIdx.x; i < NT;
         i += gridDim.x * blockDim.x) {
        if (i < N1) {
            W1h[i] = mask_at(m1, i, isB, isF) ? (half_t)W1[i] : (half_t)0.0f;
        } else if (i < N1 + N2) {
            int j = i - N1;
            W2h[j] = mask_at(m2, j, isB, isF) ? (half_t)W2[j] : (half_t)0.0f;
        } else {
            int j = i - N1 - N2;
            W3m[j] = mask_at(m3, j, isB, isF) ? W3[j] : 0.0f;
        }
    }
}

// ---------- fused GEMM (+ exact GELU): 4-phase/K-tile interleave ----------
// C[m][n] = gelu( sum_k A[m][k] * W[n][k] ), C f16 [NBATCH][HID].
// BM=256, BN=128, BK=64. 512 thr = 8 waves (2M x 4N), per-wave C = 128x32.
// Reg-staged (HK-style): global->reg (issued early) -> ds_write (late, swizzled).
// LDS: 2 slabs x (A[256][64]f16 32KB + B[128][64]f16 16KB) = 96KB, 1 block/CU.
// Element (row,kq8) at byte row*128 + ((kq^(row&7))<<4)  [kk1 frag = kk0 ^ 0x40].
// Iter kt (4 phases): compute tile kt from slab kt&1; write tile kt+1 (regs,
// loaded during iter kt-1) into other slab; issue loads tile kt+2 (P1:A, P2:B).
// vmcnt(NL) ONCE per iter at P2: retires L(kt+1) (NL ops), leaves L(kt+2).
// Each phase: {6 ds_read; stage-issue; barrier; lgkm0; SB; setprio1; 8 MFMA;
// setprio0; barrier}  (T3+T4+T5; rule-18 SB after lgkm).
template <int K, bool AF32>
__global__ __launch_bounds__(512, 2) void gemm_gelu(
    const void* __restrict__ Ain, const half_t* __restrict__ Bw,
    half_t* __restrict__ Cout) {
    constexpr int NKT = K / 64;                // 24 or 10 (even)
    constexpr int NL  = AF32 ? 10 : 6;         // VMEM ops per tile (A + B)
    static_assert(NKT >= 4 && NKT % 2 == 0, "");
    __shared__ __align__(16) char lds[98304];

    const int t = threadIdx.x, lane = t & 63, wid = t >> 6;
    const int wr = wid >> 2, wc = wid & 3;

    // XCD-bijective swizzle; nwg = 1280 = 8*160. n-fastest: 5 n-blocks of one
    // m-panel are contiguous on one XCD's L2 (x fetched ~once per panel).
    const int q       = (int)gridDim.x >> 3;
    const int logical = ((int)blockIdx.x & 7) * q + ((int)blockIdx.x >> 3);
    const int mb = logical / 5, nbk = logical - mb * 5;
    const long mBase = (long)mb * 256;
    const int  n0    = nbk * 128;

    // fragment read addresses (kk0; kk1 = ^0x40)
    int aRd[8], bRd[2];
    {
        const int rr = lane & 15, kqg = lane >> 4;
#pragma unroll
        for (int mf = 0; mf < 8; ++mf) {
            const int row = wr * 128 + mf * 16 + rr;
            aRd[mf] = row * 128 + ((kqg ^ (row & 7)) << 4);
        }
#pragma unroll
        for (int nf = 0; nf < 2; ++nf) {
            const int row = wc * 32 + nf * 16 + rr;
            bRd[nf] = 32768 + row * 128 + ((kqg ^ (row & 7)) << 4);
        }
    }

    // staging: A thread -> (row=t>>1, half hA), 128B f32 or 64B f16 per tile
    //          B thread -> (row=t>>2, quarter qB), 32B per tile
    const int rowA = t >> 1, hA = t & 1;
    const int rowB = t >> 2, qB = t & 3;
    int awA[4], bwB[2];
#pragma unroll
    for (int qq = 0; qq < 4; ++qq)
        awA[qq] = rowA * 128 + ((((hA << 2) | qq) ^ (rowA & 7)) << 4);
#pragma unroll
    for (int j = 0; j < 2; ++j)
        bwB[j] = 32768 + rowB * 128 + ((((qB << 1) | j) ^ (rowB & 7)) << 4);

    const float*  srcAf = (const float*)Ain  + (mBase + rowA) * (long)K + hA * 32;
    const half_t* srcAh = (const half_t*)Ain + (mBase + rowA) * (long)K + hA * 32;
    const half_t* srcB  = Bw + (size_t)(n0 + rowB) * K + qB * 16;

    // in-flight staging registers (2 sets, statically indexed via refs)
    float4v sAf0[8], sAf1[8];
    f16x8   sAh0[4], sAh1[4];
    f16x8   sBv0[2], sBv1[2];

    auto LAF = [&](int k, float4v (&s)[8]) {
        const float* p = srcAf + (size_t)k * 64;
#pragma unroll
        for (int i = 0; i < 8; ++i) s[i] = *(const float4v*)(p + i * 4);
    };
    auto LAH = [&](int k, f16x8 (&s)[4]) {
        const half_t* p = srcAh + (size_t)k * 64;
#pragma unroll
        for (int i = 0; i < 4; ++i) s[i] = *(const f16x8*)(p + i * 8);
    };
    auto LB = [&](int k, f16x8 (&s)[2]) {
        const half_t* p = srcB + (size_t)k * 64;
#pragma unroll
        for (int i = 0; i < 2; ++i) s[i] = *(const f16x8*)(p + i * 8);
    };
    auto WAf = [&](const float4v (&s)[8], int ob) {
#pragma unroll
        for (int qq = 0; qq < 4; ++qq) {
            f16x8 hh;
#pragma unroll
            for (int i = 0; i < 4; ++i) {
                hh[i]     = (half_t)s[2 * qq][i];
                hh[i + 4] = (half_t)s[2 * qq + 1][i];
            }
            *(f16x8*)(&lds[ob + awA[qq]]) = hh;
        }
    };
    auto WAh = [&](const f16x8 (&s)[4], int ob) {
#pragma unroll
        for (int qq = 0; qq < 4; ++qq) *(f16x8*)(&lds[ob + awA[qq]]) = s[qq];
    };
    auto WB = [&](const f16x8 (&s)[2], int ob) {
#pragma unroll
        for (int j = 0; j < 2; ++j) *(f16x8*)(&lds[ob + bwB[j]]) = s[j];
    };

    f32x4 acc[8][2];
#pragma unroll
    for (int mf = 0; mf < 8; ++mf)
#pragma unroll
        for (int nf = 0; nf < 2; ++nf) {
            f32x4 z = {0.f, 0.f, 0.f, 0.f};
            acc[mf][nf] = z;
        }

    // one phase. MHc: m-half (0/1). XKc: 0 or 0x40 (kk half). wKind: 0 none,
    // 1 = vmcnt+A-write, 2 = B-write. vmZero: use vmcnt(0) instead of NL.
    auto PHASE = [&](auto MHc, auto XKc, int cb, int ob,
                     int stA, int stB, int kL, int wKind, int vmZero,
                     float4v (&afL)[8], float4v (&afW)[8],
                     f16x8 (&ahL)[4], f16x8 (&ahW)[4],
                     f16x8 (&bL)[2], f16x8 (&bW)[2]) {
        constexpr int MH = decltype(MHc)::value;
        constexpr int XK = decltype(XKc)::value;
        f16x8 av[4], bv[2];
#pragma unroll
        for (int m2 = 0; m2 < 4; ++m2)
            av[m2] = *(const f16x8*)(&lds[cb + (aRd[MH * 4 + m2] ^ XK)]);
#pragma unroll
        for (int nf = 0; nf < 2; ++nf)
            bv[nf] = *(const f16x8*)(&lds[cb + (bRd[nf] ^ XK)]);
        if (stA) { if constexpr (AF32) LAF(kL, afL); else LAH(kL, ahL); }
        if (stB) LB(kL, bL);
        SB();
        if (wKind == 1) {
            if (vmZero) asm volatile("s_waitcnt vmcnt(0)" ::: "memory");
            else        asm volatile("s_waitcnt vmcnt(%0)" :: "i"(NL) : "memory");
            SB();
            if constexpr (AF32) WAf(afW, ob); else WAh(ahW, ob);
        } else if (wKind == 2) {
            WB(bW, ob);
        }
        __builtin_amdgcn_s_barrier();
        asm volatile("s_waitcnt lgkmcnt(0)" ::: "memory");
        SB();
        __builtin_amdgcn_s_setprio(1);
#pragma unroll
        for (int m2 = 0; m2 < 4; ++m2)
#pragma unroll
            for (int nf = 0; nf < 2; ++nf)
                acc[MH * 4 + m2][nf] = __builtin_amdgcn_mfma_f32_16x16x32_f16(
                    av[m2], bv[nf], acc[MH * 4 + m2][nf], 0, 0, 0);
        __builtin_amdgcn_s_setprio(0);
        SB();
        __builtin_amdgcn_s_barrier();
    };

    auto ITER = [&](int kt,
                    float4v (&afL)[8], float4v (&afW)[8],
                    f16x8 (&ahL)[4], f16x8 (&ahW)[4],
                    f16x8 (&bL)[2], f16x8 (&bW)[2]) {
        const int cb = (kt & 1) * 49152, ob = cb ^ 49152;
        const int hasL = (kt + 2 < NKT), hasW = (kt + 1 < NKT);
        PHASE(ic<0>{}, ic<0>{},    cb, ob, hasL, 0, kt + 2, 0, 0,
              afL, afW, ahL, ahW, bL, bW);
        PHASE(ic<1>{}, ic<0>{},    cb, ob, 0, hasL, kt + 2, hasW ? 1 : 0,
              hasL ? 0 : 1, afL, afW, ahL, ahW, bL, bW);
        PHASE(ic<0>{}, ic<0x40>{}, cb, ob, 0, 0, 0, hasW ? 2 : 0, 0,
              afL, afW, ahL, ahW, bL, bW);
        PHASE(ic<1>{}, ic<0x40>{}, cb, ob, 0, 0, 0, 0, 0,
              afL, afW, ahL, ahW, bL, bW);
    };

    // prologue: issue L(0)->set0, L(1)->set1; write tile0 into slab0
    if constexpr (AF32) { LAF(0, sAf0); } else { LAH(0, sAh0); }
    LB(0, sBv0); SB();
    if constexpr (AF32) { LAF(1, sAf1); } else { LAH(1, sAh1); }
    LB(1, sBv1); SB();
    asm volatile("s_waitcnt vmcnt(%0)" :: "i"(NL) : "memory");   // L(0) done
    SB();
    if constexpr (AF32) WAf(sAf0, 0); else WAh(sAh0, 0);
    WB(sBv0, 0);
    asm volatile("s_waitcnt lgkmcnt(0)" ::: "memory");
    __builtin_amdgcn_s_barrier();

    for (int kt = 0; kt < NKT; kt += 2) {
        ITER(kt,     sAf0, sAf1, sAh0, sAh1, sBv0, sBv1);  // load->0, write<-1
        ITER(kt + 1, sAf1, sAf0, sAh1, sAh0, sBv1, sBv0);  // load->1, write<-0
    }

    // epilogue: C/D frag col=lane&15, row=(lane>>4)*4+j (verified mapping)
    const int crow0 = (lane >> 4) * 4;
    const int ccol  = lane & 15;
#pragma unroll
    for (int mf = 0; mf < 8; ++mf)
#pragma unroll
        for (int nf = 0; nf < 2; ++nf)
#pragma unroll
            for (int j = 0; j < 4; ++j) {
                const long row = mBase + wr * 128 + mf * 16 + crow0 + j;
                const int  col = n0 + wc * 32 + nf * 16 + ccol;
                Cout[row * HID + col] = (half_t)gelu_fast(acc[mf][nf][j]);
            }
}

// ---------- layer 3: out[b][o] = sum_k h2[b][k] * W3m[o][k], K=640, O=10 ----------
__global__ __launch_bounds__(256) void layer3_kernel(
    const half_t* __restrict__ h2, const float* __restrict__ W3m,
    float* __restrict__ out) {
    const int t = threadIdx.x, lane = t & 63, w = t >> 6;
    float w3r[OUT_F][10];
#pragma unroll
    for (int o = 0; o < OUT_F; ++o)
#pragma unroll
        for (int j = 0; j < 10; ++j)
            w3r[o][j] = W3m[o * HID + j * 64 + lane];

    for (long row = (long)blockIdx.x * 4 + w; row < NBATCH; row += (long)gridDim.x * 4) {
        float acc[OUT_F];
#pragma unroll
        for (int o = 0; o < OUT_F; ++o) acc[o] = 0.f;
        const half_t* hr = h2 + row * HID;
#pragma unroll
        for (int j = 0; j < 10; ++j) {
            const float h = (float)hr[j * 64 + lane];
#pragma unroll
            for (int o = 0; o < OUT_F; ++o) acc[o] += h * w3r[o][j];
        }
#pragma unroll
        for (int o = 0; o < OUT_F; ++o) {
            float v = acc[o];
#pragma unroll
            for (int off = 32; off >= 1; off >>= 1) v += __shfl_xor(v, off);
            if (lane == o) out[row * OUT_F + o] = v;
        }
    }
}

// ---------- launch ----------

extern "C" void kernel_launch(void* const* d_in, const int* in_sizes, int n_in,
                              void* d_out, int out_size, void* d_ws, size_t ws_size,
                              hipStream_t stream) {
    const float* x  = (const float*)d_in[0];
    const float* W1 = (const float*)d_in[1];
    const float* W2 = (const float*)d_in[2];
    const float* W3 = (const float*)d_in[3];
    const void*  m1 = d_in[4];
    const void*  m2 = d_in[5];
    const void*  m3 = d_in[6];
    float* out = (float*)d_out;

    char* ws = (char*)d_ws;
    int*    flags = (int*)ws;
    half_t* W1h = (half_t*)(ws + 256);                      // 640*1536*2
    half_t* W2h = (half_t*)(ws + 256 + 1966080);            // 640*640*2
    float*  W3m = (float*)(ws + 256 + 1966080 + 819200);    // 25600
    half_t* h1  = (half_t*)(ws + 256 + 1966080 + 819200 + 25600);
    half_t* h2  = (half_t*)((char*)h1 + (size_t)NBATCH * HID * 2);

    hipMemsetAsync(flags, 0, 8, stream);
    k_detect<<<64, 256, 0, stream>>>((const unsigned*)m1, 65536, flags);
    k_mask_all<<<1024, 256, 0, stream>>>(W1, W2, W3, m1, m2, m3, W1h, W2h, W3m, flags);

    gemm_gelu<IN_F, true><<<1280, 512, 0, stream>>>((const void*)x, W1h, h1);
    gemm_gelu<HID, false><<<1280, 512, 0, stream>>>((const void*)h1, W2h, h2);
    layer3_kernel<<<2048, 256, 0, stream>>>(h2, W3m, out);
}

// Round 9
// 391.973 us; speedup vs baseline: 2.0793x; 1.4694x over previous
//
#include <hip/hip_runtime.h>
#include <hip/hip_fp16.h>
#include <math.h>

typedef _Float16 half_t;
typedef __attribute__((ext_vector_type(8))) _Float16 f16x8;  // MFMA A/B frag
typedef __attribute__((ext_vector_type(4))) float   f32x4;   // MFMA C/D frag
typedef __attribute__((ext_vector_type(4))) float   float4v;

#define IN_F   1536
#define HID    640
#define OUT_F  10
#define NBATCH 65536

#define SB() __builtin_amdgcn_sched_barrier(0)

// ---------- helpers ----------

__device__ __forceinline__ void gll16(const void* g, const void* l) {
    __builtin_amdgcn_global_load_lds(
        (const __attribute__((address_space(1))) unsigned*)g,
        (__attribute__((address_space(3))) unsigned*)l, 16, 0, 0);
}

// exact-GELU via A&S 7.1.26 erf poly (|eps|<=1.5e-7, noise vs f16 rounding)
__device__ __forceinline__ float gelu_fast(float z) {
    float x  = 0.70710678118654752f * z;
    float ax = fabsf(x);
    float t  = 1.0f / (1.0f + 0.3275911f * ax);
    float p  = t * (0.254829592f +
               t * (-0.284496736f +
               t * (1.421413741f +
               t * (-1.453152027f +
               t * 1.061405429f))));
    float e  = __expf(-ax * ax);
    float er = 1.0f - p * e;
    er = (x < 0.0f) ? -er : er;
    return 0.5f * z * (1.0f + er);
}

// ---------- prep: mask dtype detection + masked weight build ----------

__global__ void k_detect(const unsigned* __restrict__ m, int nDwords, int* flags) {
    int f = 0, g = 0;
    for (int i = blockIdx.x * blockDim.x + threadIdx.x; i < nDwords;
         i += gridDim.x * blockDim.x) {
        unsigned d = m[i];
        f |= (d == 0x3F800000u);
        g |= (d != 0u) & (d != 1u) & (d != 0x3F800000u);
    }
    if (f) atomicOr(&flags[0], 1);
    if (g) atomicOr(&flags[1], 1);
}

__device__ __forceinline__ bool mask_at(const void* mask, int i, int isB, int isF) {
    if (isB) return ((const unsigned char*)mask)[i] != 0;
    if (isF) return ((const float*)mask)[i] != 0.0f;
    return ((const int*)mask)[i] != 0;
}

__global__ void k_mask_all(const float* __restrict__ W1, const float* __restrict__ W2,
                           const float* __restrict__ W3,
                           const void* __restrict__ m1, const void* __restrict__ m2,
                           const void* __restrict__ m3,
                           half_t* __restrict__ W1h, half_t* __restrict__ W2h,
                           float* __restrict__ W3m, const int* __restrict__ flags) {
    const int isB = flags[1], isF = flags[0];
    const int N1 = HID * IN_F, N2 = HID * HID, N3 = OUT_F * HID;
    const int NT = N1 + N2 + N3;
    for (int i = blockIdx.x * blockDim.x + threadIdx.x; i < NT;
         i += gridDim.x * blockDim.x) {
        if (i < N1) {
            W1h[i] = mask_at(m1, i, isB, isF) ? (half_t)W1[i] : (half_t)0.0f;
        } else if (i < N1 + N2) {
            int j = i - N1;
            W2h[j] = mask_at(m2, j, isB, isF) ? (half_t)W2[j] : (half_t)0.0f;
        } else {
            int j = i - N1 - N2;
            W3m[j] = mask_at(m3, j, isB, isF) ? W3[j] : 0.0f;
        }
    }
}

// ---------- fused GEMM (+ exact GELU): 16-wave, gll-only, counted-vmcnt ----------
// C[m][n] = gelu( sum_k A[m][k] * W[n][k] ), C f16 [NBATCH][HID].
// BM=128, BN=320, BK=32. 1024 thr = 16 waves (4m x 4n), per-wave C = 32x80,
// acc[2][5] = 40 AGPR. All staging via global_load_lds (VGPR-light -> 16 waves
// co-resident; per-wave staging throughput ~1.9 B/cyc is the HW invariant, so
// waves x (bytes/FLOP) is the whole game).
// LDS slab: A [128 rows][128B f32 | 64B f16] + B [320 rows][64B f16]; x2 bufs.
//   AF32 slab 36KB -> 72KB total; f16 slab 28KB -> 56KB. 1 block/CU.
// Swizzle: A-f32 byte = row*128 + ((slot^(row&7))<<4); A-f16/B byte =
//   row*64 + ((slot^(row&3))<<4). gll dest linear; source pre-inverse-swizzled.
// VMEM ops/step per wave: AF32: w0-9 = 3 (A1+B2), w10-15 = 1 (A1).
//                         f16 : w0-7 = 3 (A1+B2), w8-9 = 2 (B2), w10-15 = 0.
// Ring (depth-2): entry vmcnt(Nself) retires L(ks) keeping L(ks+1); READY
// barrier; ds_read frags; lgkm(0)+SB; CONSUMED barrier; STAGE(ks+2)->cb;
// cvt(AF32); 10 MFMA.
template <int K, bool AF32>
__global__ __launch_bounds__(1024, 1) void gemm_gelu(
    const void* __restrict__ Ain, const half_t* __restrict__ Bw,
    half_t* __restrict__ Cout) {
    constexpr int NK     = K / 32;                  // 48 or 20
    constexpr int ABYTES = AF32 ? 16384 : 8192;
    constexpr int SLAB   = ABYTES + 20480;
    static_assert(NK >= 4, "");
    __shared__ __align__(16) char lds[2 * SLAB];

    const int t = threadIdx.x, lane = t & 63, wid = t >> 6;
    const int wr = wid >> 2, wc = wid & 3;

    // XCD-bijective swizzle; nwg = 1024 = 8*128, n-fastest (2 n-blocks/panel).
    const int q       = (int)gridDim.x >> 3;
    const int logical = ((int)blockIdx.x & 7) * q + ((int)blockIdx.x >> 3);
    const int mb = logical >> 1, nbk = logical & 1;
    const long mBase = (long)mb * 128;
    const int  n0    = nbk * 320;

    // ---- fragment read addresses ----
    const int rr = lane & 15, k8 = lane >> 4;
    int aRd0[2], aRd1[2], bRd[5];
#pragma unroll
    for (int mf = 0; mf < 2; ++mf) {
        const int row = wr * 32 + mf * 16 + rr;
        if constexpr (AF32) {
            aRd0[mf] = row * 128 + ((((2 * k8))     ^ (row & 7)) << 4);
            aRd1[mf] = row * 128 + ((((2 * k8) + 1) ^ (row & 7)) << 4);
        } else {
            aRd0[mf] = row * 64 + ((k8 ^ (row & 3)) << 4);
        }
    }
#pragma unroll
    for (int nf = 0; nf < 5; ++nf) {
        const int nrow = wc * 80 + nf * 16 + rr;
        bRd[nf] = ABYTES + nrow * 64 + ((k8 ^ (nrow & 3)) << 4);
    }

    // ---- staging sources (inverse-swizzled) ----
    // A f32: all 1024 thr, o=t*16: row=t>>3, slot=t&7, kq=slot^(row&7) (4 f32)
    // A f16: t<512,       o=t*16: row=t>>2, slot=t&3, kq=slot^(row&3) (8 f16)
    // B    : t<640, 2 ops, o=(t+r*640)*16: row=o>>6, slot=(o>>4)&3, kq=slot^(row&3)
    const float*  srcAf = nullptr;
    const half_t* srcAh = nullptr;
    int oA = 0;
    if constexpr (AF32) {
        const int row = t >> 3, slot = t & 7, kq = slot ^ (row & 7);
        srcAf = (const float*)Ain + (mBase + row) * (long)K + kq * 4;
        oA    = t * 16;
    } else {
        const int row = t >> 2, slot = t & 3, kq = slot ^ (row & 3);
        srcAh = (const half_t*)Ain + (mBase + row) * (long)K + kq * 8;
        oA    = t * 16;
    }
    const half_t* srcB0; const half_t* srcB1;
    int oB0, oB1;
    {
        const int o0 = t * 16,          r0 = o0 >> 6, s0 = (o0 >> 4) & 3;
        const int o1 = (t + 640) * 16,  r1 = o1 >> 6, s1 = (o1 >> 4) & 3;
        srcB0 = Bw + (size_t)(n0 + r0) * K + (s0 ^ (r0 & 3)) * 8;
        srcB1 = Bw + (size_t)(n0 + (r1 < 320 ? r1 : 0)) * K + (s1 ^ (r1 & 3)) * 8;
        oB0 = ABYTES + o0; oB1 = ABYTES + o1;
    }

    auto STAGE = [&](int k, int sb) {
        if constexpr (AF32) {
            gll16(srcAf + (size_t)k * 32, &lds[sb + oA]);
        } else {
            if (t < 512) gll16(srcAh + (size_t)k * 32, &lds[sb + oA]);
        }
        if (t < 640) {
            gll16(srcB0 + (size_t)k * 32, &lds[sb + oB0]);
            gll16(srcB1 + (size_t)k * 32, &lds[sb + oB1]);
        }
    };

    f32x4 acc[2][5];
#pragma unroll
    for (int mf = 0; mf < 2; ++mf)
#pragma unroll
        for (int nf = 0; nf < 5; ++nf) {
            f32x4 z = {0.f, 0.f, 0.f, 0.f};
            acc[mf][nf] = z;
        }

    // prologue: oldest-first L(0), L(1)
    STAGE(0, 0); SB();
    STAGE(1, SLAB); SB();

    for (int ks = 0; ks < NK; ++ks) {
        const int cb = (ks & 1) * SLAB;
        // entry: retire L(ks), keep L(ks+1) in flight (per-wave op counts)
        if (ks + 1 < NK) {
            if constexpr (AF32) {
                if (wid < 10) asm volatile("s_waitcnt vmcnt(3)" ::: "memory");
                else          asm volatile("s_waitcnt vmcnt(1)" ::: "memory");
            } else {
                if (wid < 8)       asm volatile("s_waitcnt vmcnt(3)" ::: "memory");
                else if (wid < 10) asm volatile("s_waitcnt vmcnt(2)" ::: "memory");
                else               asm volatile("s_waitcnt vmcnt(0)" ::: "memory");
            }
        } else {
            asm volatile("s_waitcnt vmcnt(0)" ::: "memory");
        }
        __builtin_amdgcn_s_barrier();                    // READY: slab ks complete
        // fragment reads
        float4v alo[2], ahi[2];
        f16x8 av[2], bv[5];
        if constexpr (AF32) {
#pragma unroll
            for (int mf = 0; mf < 2; ++mf) {
                alo[mf] = *(const float4v*)(&lds[cb + aRd0[mf]]);
                ahi[mf] = *(const float4v*)(&lds[cb + aRd1[mf]]);
            }
        } else {
#pragma unroll
            for (int mf = 0; mf < 2; ++mf)
                av[mf] = *(const f16x8*)(&lds[cb + aRd0[mf]]);
        }
#pragma unroll
        for (int nf = 0; nf < 5; ++nf)
            bv[nf] = *(const f16x8*)(&lds[cb + bRd[nf]]);
        asm volatile("s_waitcnt lgkmcnt(0)" ::: "memory");
        SB();                                             // rule 18
        if (ks + 2 < NK) {
            __builtin_amdgcn_s_barrier();                 // CONSUMED: safe to overwrite
            STAGE(ks + 2, cb);
            SB();
        }
        if constexpr (AF32) {
#pragma unroll
            for (int mf = 0; mf < 2; ++mf) {
                f16x8 h;
#pragma unroll
                for (int i = 0; i < 4; ++i) {
                    h[i]     = (half_t)alo[mf][i];
                    h[i + 4] = (half_t)ahi[mf][i];
                }
                av[mf] = h;
            }
        }
#pragma unroll
        for (int mf = 0; mf < 2; ++mf)
#pragma unroll
            for (int nf = 0; nf < 5; ++nf)
                acc[mf][nf] = __builtin_amdgcn_mfma_f32_16x16x32_f16(
                    av[mf], bv[nf], acc[mf][nf], 0, 0, 0);
    }

    // epilogue: C/D frag col=lane&15, row=(lane>>4)*4+j (verified mapping)
    const int crow0 = (lane >> 4) * 4;
    const int ccol  = lane & 15;
#pragma unroll
    for (int mf = 0; mf < 2; ++mf)
#pragma unroll
        for (int nf = 0; nf < 5; ++nf)
#pragma unroll
            for (int j = 0; j < 4; ++j) {
                const long row = mBase + wr * 32 + mf * 16 + crow0 + j;
                const int  col = n0 + wc * 80 + nf * 16 + ccol;
                Cout[row * HID + col] = (half_t)gelu_fast(acc[mf][nf][j]);
            }
}

// ---------- layer 3: out[b][o] = sum_k h2[b][k] * W3m[o][k], K=640, O=10 ----------
__global__ __launch_bounds__(256) void layer3_kernel(
    const half_t* __restrict__ h2, const float* __restrict__ W3m,
    float* __restrict__ out) {
    const int t = threadIdx.x, lane = t & 63, w = t >> 6;
    float w3r[OUT_F][10];
#pragma unroll
    for (int o = 0; o < OUT_F; ++o)
#pragma unroll
        for (int j = 0; j < 10; ++j)
            w3r[o][j] = W3m[o * HID + j * 64 + lane];

    for (long row = (long)blockIdx.x * 4 + w; row < NBATCH; row += (long)gridDim.x * 4) {
        float acc[OUT_F];
#pragma unroll
        for (int o = 0; o < OUT_F; ++o) acc[o] = 0.f;
        const half_t* hr = h2 + row * HID;
#pragma unroll
        for (int j = 0; j < 10; ++j) {
            const float h = (float)hr[j * 64 + lane];
#pragma unroll
            for (int o = 0; o < OUT_F; ++o) acc[o] += h * w3r[o][j];
        }
#pragma unroll
        for (int o = 0; o < OUT_F; ++o) {
            float v = acc[o];
#pragma unroll
            for (int off = 32; off >= 1; off >>= 1) v += __shfl_xor(v, off);
            if (lane == o) out[row * OUT_F + o] = v;
        }
    }
}

// ---------- launch ----------

extern "C" void kernel_launch(void* const* d_in, const int* in_sizes, int n_in,
                              void* d_out, int out_size, void* d_ws, size_t ws_size,
                              hipStream_t stream) {
    const float* x  = (const float*)d_in[0];
    const float* W1 = (const float*)d_in[1];
    const float* W2 = (const float*)d_in[2];
    const float* W3 = (const float*)d_in[3];
    const void*  m1 = d_in[4];
    const void*  m2 = d_in[5];
    const void*  m3 = d_in[6];
    float* out = (float*)d_out;

    char* ws = (char*)d_ws;
    int*    flags = (int*)ws;
    half_t* W1h = (half_t*)(ws + 256);                      // 640*1536*2
    half_t* W2h = (half_t*)(ws + 256 + 1966080);            // 640*640*2
    float*  W3m = (float*)(ws + 256 + 1966080 + 819200);    // 25600
    half_t* h1  = (half_t*)(ws + 256 + 1966080 + 819200 + 25600);
    half_t* h2  = (half_t*)((char*)h1 + (size_t)NBATCH * HID * 2);

    hipMemsetAsync(flags, 0, 8, stream);
    k_detect<<<64, 256, 0, stream>>>((const unsigned*)m1, 65536, flags);
    k_mask_all<<<1024, 256, 0, stream>>>(W1, W2, W3, m1, m2, m3, W1h, W2h, W3m, flags);

    gemm_gelu<IN_F, true><<<1024, 1024, 0, stream>>>((const void*)x, W1h, h1);
    gemm_gelu<HID, false><<<1024, 1024, 0, stream>>>((const void*)h1, W2h, h2);
    layer3_kernel<<<2048, 256, 0, stream>>>(h2, W3m, out);
}